// Round 8
// baseline (485.963 us; speedup 1.0000x reference)
//
#include <hip/hip_runtime.h>

// VectorQuantizer forward — outputs f32, concatenated:
//   out[0..8388608)        = z_e (STE forward value == z), NHWC order
//   out[8388608..8519680)  = argmin indices as f32, row (b,c,h) = z_e[b,h,:,c]
//   out[8519680]           = 0.25 * mean((z_q - z)^2)
//
// Two-phase argmin (R7 semantics, unchanged):
//   Phase A: f32-FMA dots, per-row min/second-min/first-argmin.
//   Phase B: rows with min2-min1 <= EPS_GAP re-scanned exactly
//            (B = fl(f64 dot), score = fl(fl(A-2B)+C), first-min tie-break).
// R8 change: double-buffered et2 with register-prefetched staging (one barrier
// per k-tile, global latency hidden under the FMA loop), 3 blocks/CU.

#define N_Z 8388608   // 32*64*64*64
#define N_IDX 131072  // 32*64*64
#define K_EMB 1024
#define D_EMB 64
#define EPS_GAP 7e-5f // rigorous bound 4.2e-5; 1.67x safety

__global__ __launch_bounds__(256) void ek2f_kernel(
    const float* __restrict__ emb, float* __restrict__ ek2f) {
  int k = blockIdx.x * 256 + threadIdx.x;   // 4 blocks -> 1024
  const float* row = emb + (size_t)k * D_EMB;
  float s = 0.0f;
  for (int d = 0; d < D_EMB; d++) {
    float e = row[d];
    float sq = e * e;
    asm volatile("" : "+v"(sq));   // block FMA-contraction / reassociation
    s = s + sq;
  }
  ek2f[k] = s;
}

// One block per (b,h): z tile z_e[b,h,:,:] is a contiguous [w=64][c=64] block.
// 256 threads = 16 c-groups (i4 = t>>4) x 16 k-lanes (j = t&15, k = kt*64+j+16s).
__global__ __launch_bounds__(256) void vq_main_kernel(
    const float* __restrict__ z, const float* __restrict__ emb,
    const float* __restrict__ ek2g, float* __restrict__ out_idx,
    double* __restrict__ loss_acc) {
  __shared__ __align__(16) float zts[64][64];      // [w][c] 16 KB
  __shared__ __align__(16) float et2[2][64][64];   // [w][(k&15)*4+(k>>4)] 32 KB
  __shared__ float sk2[K_EMB];                     // 4 KB
  __shared__ float sa[64];
  __shared__ int sidx[64];
  __shared__ int sflag[64];
  __shared__ double lred[16];
  __shared__ float wrv[4];
  __shared__ int wri[4];

  const int t = threadIdx.x;
  const int bid = blockIdx.x;     // = b*64 + h
  const int j = t & 15;           // k lane
  const int i4 = t >> 4;          // c group

  // staging geometry (same mapping as R7): thread covers k-row kk = t&63,
  // float4 quarters w4 = (t>>6) + q*4, LDS col = (kk&15)*4 + (kk>>4)
  const int kk = t & 63;
  const int w4b = t >> 6;
  const int col = (kk & 15) * 4 + (kk >> 4);

  // ---- stage z tile, sk2, and k-tile 0 (reg-prefetched) ----
  const float4* zt4 = (const float4*)(z + (size_t)bid * 4096);
  float4 pf[4];
  #pragma unroll
  for (int q = 0; q < 4; q++)
    pf[q] = *(const float4*)(emb + (size_t)kk * 64 + (w4b + q * 4) * 4);
  #pragma unroll
  for (int q = 0; q < 4; q++) {
    int p = t + q * 256;          // float4 index 0..1023
    float4 v = zt4[p];
    *(float4*)&zts[p >> 4][(p & 15) * 4] = v;
  }
  #pragma unroll
  for (int q = 0; q < 4; q++) sk2[t + q * 256] = ek2g[t + q * 256];
  #pragma unroll
  for (int q = 0; q < 4; q++) {
    int w4 = w4b + q * 4;
    et2[0][w4 * 4 + 0][col] = pf[q].x; et2[0][w4 * 4 + 1][col] = pf[q].y;
    et2[0][w4 * 4 + 2][col] = pf[q].z; et2[0][w4 * 4 + 3][col] = pf[q].w;
  }
  __syncthreads();

  // ---- A[c]: strict sequential f32 sum of fl(z_d^2) (bit-exact, as R6/R7) ----
  if (t < 64) {
    float a = 0.0f;
    for (int w = 0; w < 64; w++) {
      float zf = zts[w][t];
      float sq = zf * zf;
      asm volatile("" : "+v"(sq));
      a = a + sq;
    }
    sa[t] = a;
  }
  __syncthreads();

  float A_[4];
  #pragma unroll
  for (int ci = 0; ci < 4; ci++) A_[ci] = sa[i4 * 4 + ci];

  float m1[4], m2[4];
  int i1[4];
  #pragma unroll
  for (int ci = 0; ci < 4; ci++) { m1[ci] = 3.0e38f; m2[ci] = 3.0e38f; i1[ci] = 0; }

  for (int kt = 0; kt < 16; kt++) {
    const int cur = kt & 1;
    // ---- prefetch next k-tile into registers (latency hides under FMAs) ----
    if (kt < 15) {
      const float* src = emb + (size_t)((kt + 1) * 64 + kk) * 64;
      #pragma unroll
      for (int q = 0; q < 4; q++)
        pf[q] = *(const float4*)(src + (w4b + q * 4) * 4);
    }

    float acc[4][4];
    #pragma unroll
    for (int ci = 0; ci < 4; ci++)
      #pragma unroll
      for (int s = 0; s < 4; s++) acc[ci][s] = 0.0f;

    #pragma unroll 8
    for (int w = 0; w < 64; w++) {
      float4 zr = *(const float4*)&zts[w][i4 * 4];        // broadcast
      float4 er = *(const float4*)&et2[cur][w][j * 4];    // 2-way (free)
      acc[0][0] += zr.x * er.x; acc[0][1] += zr.x * er.y;
      acc[0][2] += zr.x * er.z; acc[0][3] += zr.x * er.w;
      acc[1][0] += zr.y * er.x; acc[1][1] += zr.y * er.y;
      acc[1][2] += zr.y * er.z; acc[1][3] += zr.y * er.w;
      acc[2][0] += zr.z * er.x; acc[2][1] += zr.z * er.y;
      acc[2][2] += zr.z * er.z; acc[2][3] += zr.z * er.w;
      acc[3][0] += zr.w * er.x; acc[3][1] += zr.w * er.y;
      acc[3][2] += zr.w * er.z; acc[3][3] += zr.w * er.w;
    }

    // ---- approx scores; track min / second-min / first-argmin ----
    #pragma unroll
    for (int s = 0; s < 4; s++) {
      int k = kt * 64 + j + 16 * s;
      float ck = sk2[k];
      #pragma unroll
      for (int ci = 0; ci < 4; ci++) {
        float sc = fmaf(-2.0f, acc[ci][s], A_[ci]) + ck;
        if (sc < m1[ci]) { m2[ci] = m1[ci]; m1[ci] = sc; i1[ci] = k; }
        else             { m2[ci] = fminf(m2[ci], sc); }   // sc==m1 -> m2=m1 (flag)
      }
    }

    // ---- write prefetched tile to the other buffer; one barrier per kt ----
    if (kt < 15) {
      #pragma unroll
      for (int q = 0; q < 4; q++) {
        int w4 = w4b + q * 4;
        et2[cur ^ 1][w4 * 4 + 0][col] = pf[q].x;
        et2[cur ^ 1][w4 * 4 + 1][col] = pf[q].y;
        et2[cur ^ 1][w4 * 4 + 2][col] = pf[q].z;
        et2[cur ^ 1][w4 * 4 + 3][col] = pf[q].w;
      }
    }
    __syncthreads();
  }

  // ---- 16-lane top-2 lex merge per c ----
  #pragma unroll
  for (int ci = 0; ci < 4; ci++) {
    float v1 = m1[ci], v2 = m2[ci];
    int ix = i1[ci];
    #pragma unroll
    for (int m = 8; m; m >>= 1) {
      float ov1 = __shfl_xor(v1, m, 16);
      int oi1 = __shfl_xor(ix, m, 16);
      float ov2 = __shfl_xor(v2, m, 16);
      if (ov1 < v1)      { v2 = fminf(v1, ov2); v1 = ov1; ix = oi1; }
      else if (ov1 > v1) { v2 = fminf(v2, ov1); }
      else               { v2 = v1; ix = min(ix, oi1); }   // tie -> force flag
    }
    m1[ci] = v1; m2[ci] = v2; i1[ci] = ix;
  }
  if (j == 0) {
    #pragma unroll
    for (int ci = 0; ci < 4; ci++) {
      int c = i4 * 4 + ci;
      sidx[c] = i1[ci];
      sflag[c] = (m2[ci] - m1[ci] <= EPS_GAP) ? 1 : 0;
    }
  }
  __syncthreads();

  // ---- Phase B: exact re-scan of flagged rows (rare) ----
  for (int c = 0; c < 64; c++) {
    if (!sflag[c]) continue;                 // uniform
    float A = sa[c];
    float lm = 3.0e38f;
    int li = 0;
    #pragma unroll
    for (int r = 0; r < 4; r++) {
      int k = t + 256 * r;
      double B = 0.0;
      const float4* e4 = (const float4*)(emb + (size_t)k * 64);
      for (int w4 = 0; w4 < 16; w4++) {
        float4 e = e4[w4];
        B += (double)zts[w4 * 4 + 0][c] * (double)e.x;
        B += (double)zts[w4 * 4 + 1][c] * (double)e.y;
        B += (double)zts[w4 * 4 + 2][c] * (double)e.z;
        B += (double)zts[w4 * 4 + 3][c] * (double)e.w;
      }
      float Bf = (float)B;
      float t1 = A - 2.0f * Bf;              // 2*Bf exact -> single rounding
      float sc = t1 + sk2[k];
      if (sc < lm) { lm = sc; li = k; }      // k ascending -> first-min kept
    }
    #pragma unroll
    for (int m = 32; m; m >>= 1) {
      float ov = __shfl_xor(lm, m);
      int oi = __shfl_xor(li, m);
      if (ov < lm || (ov == lm && oi < li)) { lm = ov; li = oi; }
    }
    int wid = t >> 6;
    if ((t & 63) == 0) { wrv[wid] = lm; wri[wid] = li; }
    __syncthreads();
    if (t == 0) {
      float bv = wrv[0]; int bi = wri[0];
      #pragma unroll
      for (int q = 1; q < 4; q++) {
        if (wrv[q] < bv || (wrv[q] == bv && wri[q] < bi)) { bv = wrv[q]; bi = wri[q]; }
      }
      sidx[c] = bi;
    }
    __syncthreads();
  }
  __syncthreads();

  // ---- write indices ----
  const int b = bid >> 6, h = bid & 63;
  if (t < 64) out_idx[(size_t)b * 4096 + t * 64 + h] = (float)sidx[t];

  // ---- loss: sum (z - e[idx])^2 in f64 ----
  double ls = 0.0;
  #pragma unroll
  for (int ci = 0; ci < 4; ci++) {
    int c = i4 * 4 + ci;
    const float* er = emb + (size_t)sidx[c] * 64;
    #pragma unroll
    for (int s = 0; s < 4; s++) {
      int w = j + 16 * s;
      double d = (double)zts[w][c] - (double)er[w];
      ls += d * d;
    }
  }
  #pragma unroll
  for (int m = 8; m; m >>= 1) ls += __shfl_xor(ls, m, 16);
  if (j == 0) lred[i4] = ls;
  __syncthreads();
  if (t == 0) {
    double s = 0.0;
    #pragma unroll
    for (int q = 0; q < 16; q++) s += lred[q];
    atomicAdd(loss_acc, s);
  }
}

__global__ void loss_final_kernel(const double* __restrict__ acc,
                                  float* __restrict__ out_loss) {
  *out_loss = (float)(0.25 * (*acc) / (double)N_Z);
}

extern "C" void kernel_launch(void* const* d_in, const int* in_sizes, int n_in,
                              void* d_out, int out_size, void* d_ws, size_t ws_size,
                              hipStream_t stream) {
  const float* z = (const float*)d_in[0];     // [32,64,64,64] NHWC
  const float* emb = (const float*)d_in[1];   // [1024,64]
  float* out = (float*)d_out;

  float* ek2f = (float*)d_ws;                            // 1024 floats
  double* lacc = (double*)((char*)d_ws + 4096);          // 1 double, aligned

  (void)hipMemsetAsync(lacc, 0, sizeof(double), stream);
  // out[0] = z (STE forward value): raw f32 device-to-device copy
  (void)hipMemcpyAsync(out, z, (size_t)N_Z * sizeof(float),
                       hipMemcpyDeviceToDevice, stream);
  ek2f_kernel<<<4, 256, 0, stream>>>(emb, ek2f);
  vq_main_kernel<<<2048, 256, 0, stream>>>(z, emb, ek2f, out + N_Z, lacc);
  loss_final_kernel<<<1, 1, 0, stream>>>(lacc, out + N_Z + N_IDX);
}

// Round 9
// 447.912 us; speedup vs baseline: 1.0850x; 1.0850x over previous
//
#include <hip/hip_runtime.h>

// VectorQuantizer forward — outputs f32, concatenated:
//   out[0..8388608)        = z_e (STE forward value == z), NHWC order
//   out[8388608..8519680)  = argmin indices as f32, row (b,c,h) = z_e[b,h,:,c]
//   out[8519680]           = 0.25 * mean((z_q - z)^2)
//
// R9: Phase A via MFMA bf16 error-split (z=zh+zl, e=eh+el; hh+hl+lh passes),
// 6x mfma_f32_16x16x32_bf16 per 16x16 score tile. Gap-flagged rows re-scanned
// in phase B with exact R7 semantics (f64 dot, fl(fl(A-2B)+C), first-min).
// A[c], C[k] bit-exact sequential f32 sums (unchanged since R6).

#define N_Z 8388608   // 32*64*64*64
#define N_IDX 131072  // 32*64*64
#define K_EMB 1024
#define D_EMB 64
#define EPS_GAP 1.25e-4f  // rigorous flip bound ~7e-5; 1.8x safety

typedef __attribute__((ext_vector_type(8))) short bf16x8;
typedef __attribute__((ext_vector_type(4))) float f32x4;

// f32 -> bf16 bits, round-to-nearest-even
__device__ __forceinline__ unsigned short f2bf(float f) {
  unsigned u = __builtin_bit_cast(unsigned, f);
  unsigned r = 0x7fffu + ((u >> 16) & 1u);
  return (unsigned short)((u + r) >> 16);
}
__device__ __forceinline__ float bf2f(unsigned short b) {
  return __builtin_bit_cast(float, (unsigned)b << 16);
}

__global__ __launch_bounds__(256) void ek2f_kernel(
    const float* __restrict__ emb, float* __restrict__ ek2f) {
  int k = blockIdx.x * 256 + threadIdx.x;   // 4 blocks -> 1024
  const float* row = emb + (size_t)k * D_EMB;
  float s = 0.0f;
  for (int d = 0; d < D_EMB; d++) {
    float e = row[d];
    float sq = e * e;
    asm volatile("" : "+v"(sq));   // block FMA-contraction / reassociation
    s = s + sq;
  }
  ek2f[k] = s;
}

// Pre-swizzle emb into MFMA B-fragment-linear bf16 hi/lo arrays.
// Fragment order: idx = ((kt*2 + s)*64 + l)*8 + i  where
//   k = kt*16 + (l&15),  w = s*32 + (l>>4)*8 + i,  value = e[k][w].
__global__ __launch_bounds__(256) void ebf_prep_kernel(
    const float* __restrict__ emb, unsigned short* __restrict__ ehi,
    unsigned short* __restrict__ elo) {
  int gid = blockIdx.x * 256 + threadIdx.x;   // 32 blocks -> 8192
  int k = gid >> 3, oct = gid & 7;            // w-octet = oct*8 .. oct*8+7
  const float* src = emb + (size_t)k * 64 + oct * 8;
  int kt = k >> 4, sp = oct >> 2, l = (oct & 3) * 16 + (k & 15);
  size_t off = ((size_t)((kt * 2 + sp) * 64 + l)) * 8;
  bf16x8 h8, l8;
  #pragma unroll
  for (int i = 0; i < 8; i++) {
    float v = src[i];
    unsigned short hb = f2bf(v);
    float lf = v - bf2f(hb);       // exact
    h8[i] = (short)hb;
    l8[i] = (short)f2bf(lf);
  }
  *(bf16x8*)(ehi + off) = h8;
  *(bf16x8*)(elo + off) = l8;
}

// One block per (b,h). 4 waves; wave wv computes score rows c in [wv*16, wv*16+16)
// for all 1024 k via 64 16x16 MFMA tiles (6 mfma each). K-chunks of 64 double-
// buffered in LDS (fragment-linear => memcpy staging, conflict-free ds_read_b128).
__global__ __launch_bounds__(256) void vq_main_kernel(
    const float* __restrict__ z, const float* __restrict__ emb,
    const float* __restrict__ ek2g,
    const unsigned short* __restrict__ ehi_g,
    const unsigned short* __restrict__ elo_g,
    float* __restrict__ out_idx, double* __restrict__ loss_acc) {
  __shared__ __align__(16) float zts[64][64];          // [w][c] 16 KB
  __shared__ __align__(16) unsigned short lhi[2][4096]; // 8 KB x2
  __shared__ __align__(16) unsigned short llo[2][4096]; // 8 KB x2
  __shared__ float sk2[K_EMB];                         // 4 KB
  __shared__ float sa[64];
  __shared__ int sidx[64];
  __shared__ int sflag[64];
  __shared__ double lred[16];
  __shared__ float wrv[4];
  __shared__ int wri[4];

  const int t = threadIdx.x;
  const int bid = blockIdx.x;     // = b*64 + h
  const int l = t & 63;           // lane
  const int wv = t >> 6;          // wave id; c-base = wv*16
  const int cb = wv * 16;

  // ---- stage z tile [w][c] (f32), sk2, and e-chunk 0 ----
  const float4* zt4 = (const float4*)(z + (size_t)bid * 4096);
  #pragma unroll
  for (int q = 0; q < 4; q++) {
    int p = t + q * 256;
    float4 v = zt4[p];
    *(float4*)&zts[p >> 4][(p & 15) * 4] = v;
  }
  #pragma unroll
  for (int q = 0; q < 4; q++) sk2[t + q * 256] = ek2g[t + q * 256];
  {
    const int tt = t & 127;
    const uint4* src = (t < 128) ? (const uint4*)ehi_g : (const uint4*)elo_g;
    unsigned short* dst = (t < 128) ? lhi[0] : llo[0];
    #pragma unroll
    for (int q = 0; q < 4; q++)
      *(uint4*)&dst[tt * 32 + q * 8] = src[tt * 4 + q];
  }
  __syncthreads();

  // ---- A[c]: strict sequential f32 sum of fl(z^2) (bit-exact, as R6/R7) ----
  if (t < 64) {
    float a = 0.0f;
    for (int w = 0; w < 64; w++) {
      float zf = zts[w][t];
      float sq = zf * zf;
      asm volatile("" : "+v"(sq));
      a = a + sq;
    }
    sa[t] = a;
  }

  // ---- build persistent A-fragments: zh/zl for splits s=0,1 ----
  // A[m][wloc]: lane supplies m = l&15 (c = cb+m), wloc = (l>>4)*8 + i.
  bf16x8 zh0, zh1, zl0, zl1;
  {
    const int crow = cb + (l & 15);
    const int wb = (l >> 4) * 8;
    #pragma unroll
    for (int i = 0; i < 8; i++) {
      float zf = zts[wb + i][crow];
      unsigned short hb = f2bf(zf);
      float lf = zf - bf2f(hb);
      zh0[i] = (short)hb; zl0[i] = (short)f2bf(lf);
      float zf1 = zts[32 + wb + i][crow];
      unsigned short hb1 = f2bf(zf1);
      float lf1 = zf1 - bf2f(hb1);
      zh1[i] = (short)hb1; zl1[i] = (short)f2bf(lf1);
    }
  }
  __syncthreads();   // sa visible

  float A_[4];
  #pragma unroll
  for (int i = 0; i < 4; i++) A_[i] = sa[cb + ((l >> 4) & 3) * 4 + i];

  float m1[4], m2[4];
  int i1[4];
  #pragma unroll
  for (int i = 0; i < 4; i++) { m1[i] = 3.0e38f; m2[i] = 3.0e38f; i1[i] = 0; }

  // ---- main loop: 16 k-chunks of 64 ----
  for (int ch = 0; ch < 16; ch++) {
    const int cur = ch & 1;
    uint4 pf[4];
    if (ch < 15) {   // prefetch next chunk into regs (hides under MFMAs)
      const int tt = t & 127;
      const uint4* src = (t < 128) ? (const uint4*)ehi_g : (const uint4*)elo_g;
      #pragma unroll
      for (int q = 0; q < 4; q++)
        pf[q] = src[(size_t)(ch + 1) * 512 + tt * 4 + q];
    }

    #pragma unroll
    for (int t4 = 0; t4 < 4; t4++) {
      const int fb = (t4 * 2) * 64 * 8 + l * 8;       // split 0 frag offset
      bf16x8 bh0 = *(const bf16x8*)&lhi[cur][fb];
      bf16x8 bh1 = *(const bf16x8*)&lhi[cur][fb + 512];
      bf16x8 bl0 = *(const bf16x8*)&llo[cur][fb];
      bf16x8 bl1 = *(const bf16x8*)&llo[cur][fb + 512];
      f32x4 acc = {0.f, 0.f, 0.f, 0.f};
      acc = __builtin_amdgcn_mfma_f32_16x16x32_bf16(zh0, bh0, acc, 0, 0, 0);
      acc = __builtin_amdgcn_mfma_f32_16x16x32_bf16(zh1, bh1, acc, 0, 0, 0);
      acc = __builtin_amdgcn_mfma_f32_16x16x32_bf16(zh0, bl0, acc, 0, 0, 0);
      acc = __builtin_amdgcn_mfma_f32_16x16x32_bf16(zh1, bl1, acc, 0, 0, 0);
      acc = __builtin_amdgcn_mfma_f32_16x16x32_bf16(zl0, bh0, acc, 0, 0, 0);
      acc = __builtin_amdgcn_mfma_f32_16x16x32_bf16(zl1, bh1, acc, 0, 0, 0);

      // C/D layout: col k = l&15, row c = cb + (l>>4)*4 + i
      const int k = ch * 64 + t4 * 16 + (l & 15);
      const float ck = sk2[k];
      #pragma unroll
      for (int i = 0; i < 4; i++) {
        float sc = fmaf(-2.0f, acc[i], A_[i]) + ck;
        if (sc < m1[i]) { m2[i] = m1[i]; m1[i] = sc; i1[i] = k; }
        else            { m2[i] = fminf(m2[i], sc); }   // sc==m1 -> m2=m1 (flag)
      }
    }

    if (ch < 15) {
      const int tt = t & 127;
      unsigned short* dst = (t < 128) ? lhi[cur ^ 1] : llo[cur ^ 1];
      #pragma unroll
      for (int q = 0; q < 4; q++)
        *(uint4*)&dst[tt * 32 + q * 8] = pf[q];
    }
    __syncthreads();
  }

  // ---- 16-lane top-2 lex merge per c (same grouping as R7: c=(t>>4)*4+i) ----
  #pragma unroll
  for (int ci = 0; ci < 4; ci++) {
    float v1 = m1[ci], v2 = m2[ci];
    int ix = i1[ci];
    #pragma unroll
    for (int m = 8; m; m >>= 1) {
      float ov1 = __shfl_xor(v1, m, 16);
      int oi1 = __shfl_xor(ix, m, 16);
      float ov2 = __shfl_xor(v2, m, 16);
      if (ov1 < v1)      { v2 = fminf(v1, ov2); v1 = ov1; ix = oi1; }
      else if (ov1 > v1) { v2 = fminf(v2, ov1); }
      else               { v2 = v1; ix = min(ix, oi1); }   // tie -> force flag
    }
    m1[ci] = v1; m2[ci] = v2; i1[ci] = ix;
  }
  if ((t & 15) == 0) {
    #pragma unroll
    for (int ci = 0; ci < 4; ci++) {
      int c = (t >> 4) * 4 + ci;
      sidx[c] = i1[ci];
      sflag[c] = (m2[ci] - m1[ci] <= EPS_GAP) ? 1 : 0;
    }
  }
  __syncthreads();

  // ---- Phase B: exact re-scan of flagged rows (rare) — verbatim R7 ----
  for (int c = 0; c < 64; c++) {
    if (!sflag[c]) continue;                 // uniform
    float A = sa[c];
    float lm = 3.0e38f;
    int li = 0;
    #pragma unroll
    for (int r = 0; r < 4; r++) {
      int k = t + 256 * r;
      double B = 0.0;
      const float4* e4 = (const float4*)(emb + (size_t)k * 64);
      for (int w4 = 0; w4 < 16; w4++) {
        float4 e = e4[w4];
        B += (double)zts[w4 * 4 + 0][c] * (double)e.x;
        B += (double)zts[w4 * 4 + 1][c] * (double)e.y;
        B += (double)zts[w4 * 4 + 2][c] * (double)e.z;
        B += (double)zts[w4 * 4 + 3][c] * (double)e.w;
      }
      float Bf = (float)B;
      float t1 = A - 2.0f * Bf;              // 2*Bf exact -> single rounding
      float sc = t1 + sk2[k];
      if (sc < lm) { lm = sc; li = k; }      // k ascending -> first-min kept
    }
    #pragma unroll
    for (int m = 32; m; m >>= 1) {
      float ov = __shfl_xor(lm, m);
      int oi = __shfl_xor(li, m);
      if (ov < lm || (ov == lm && oi < li)) { lm = ov; li = oi; }
    }
    if ((t & 63) == 0) { wrv[t >> 6] = lm; wri[t >> 6] = li; }
    __syncthreads();
    if (t == 0) {
      float bv = wrv[0]; int bi = wri[0];
      #pragma unroll
      for (int q = 1; q < 4; q++) {
        if (wrv[q] < bv || (wrv[q] == bv && wri[q] < bi)) { bv = wrv[q]; bi = wri[q]; }
      }
      sidx[c] = bi;
    }
    __syncthreads();
  }
  __syncthreads();

  // ---- write indices ----
  const int b = bid >> 6, h = bid & 63;
  if (t < 64) out_idx[(size_t)b * 4096 + t * 64 + h] = (float)sidx[t];

  // ---- loss: sum (z - e[idx])^2 in f64 (verbatim R7) ----
  double ls = 0.0;
  #pragma unroll
  for (int ci = 0; ci < 4; ci++) {
    int c = (t >> 4) * 4 + ci;
    const float* er = emb + (size_t)sidx[c] * 64;
    #pragma unroll
    for (int s = 0; s < 4; s++) {
      int w = (t & 15) + 16 * s;
      double d = (double)zts[w][c] - (double)er[w];
      ls += d * d;
    }
  }
  #pragma unroll
  for (int m = 8; m; m >>= 1) ls += __shfl_xor(ls, m, 16);
  if ((t & 15) == 0) lred[t >> 4] = ls;
  __syncthreads();
  if (t == 0) {
    double s = 0.0;
    #pragma unroll
    for (int q = 0; q < 16; q++) s += lred[q];
    atomicAdd(loss_acc, s);
  }
}

__global__ void loss_final_kernel(const double* __restrict__ acc,
                                  float* __restrict__ out_loss) {
  *out_loss = (float)(0.25 * (*acc) / (double)N_Z);
}

extern "C" void kernel_launch(void* const* d_in, const int* in_sizes, int n_in,
                              void* d_out, int out_size, void* d_ws, size_t ws_size,
                              hipStream_t stream) {
  const float* z = (const float*)d_in[0];     // [32,64,64,64] NHWC
  const float* emb = (const float*)d_in[1];   // [1024,64]
  float* out = (float*)d_out;

  float* ek2f = (float*)d_ws;                              // 4 KB @ 0
  double* lacc = (double*)((char*)d_ws + 4096);            // 8 B
  unsigned short* ehi = (unsigned short*)((char*)d_ws + 8192);    // 128 KB
  unsigned short* elo = (unsigned short*)((char*)d_ws + 8192 + 131072); // 128 KB

  (void)hipMemsetAsync(lacc, 0, sizeof(double), stream);
  // out[0] = z (STE forward value): raw f32 device-to-device copy
  (void)hipMemcpyAsync(out, z, (size_t)N_Z * sizeof(float),
                       hipMemcpyDeviceToDevice, stream);
  ek2f_kernel<<<4, 256, 0, stream>>>(emb, ek2f);
  ebf_prep_kernel<<<32, 256, 0, stream>>>(emb, ehi, elo);
  vq_main_kernel<<<2048, 256, 0, stream>>>(z, emb, ek2f, ehi, elo,
                                           out + N_Z, lacc);
  loss_final_kernel<<<1, 1, 0, stream>>>(lacc, out + N_Z + N_IDX);
}

// Round 10
// 439.701 us; speedup vs baseline: 1.1052x; 1.0187x over previous
//
#include <hip/hip_runtime.h>

// VectorQuantizer forward — outputs f32, concatenated:
//   out[0..8388608)        = z_e (STE forward value == z), NHWC order
//   out[8388608..8519680)  = argmin indices as f32, row (b,c,h) = z_e[b,h,:,c]
//   out[8519680]           = 0.25 * mean((z_q - z)^2)
//
// R10: barrier-free MFMA main loop. B-fragments (bf16 hi/lo error-split,
// fragment-linear) read directly from global (L2-resident 256 KB table) — no
// LDS staging, no main-loop __syncthreads. 2 z-tiles per block => 12 MFMA per
// fragment-set, 1536 MFMA/wave. out[0] written during z staging (no memcpy).
// Phase B (exact f64 re-scan of gap-flagged rows), A/C sums, merge, loss:
// verbatim R7/R9 semantics.

#define N_Z 8388608   // 32*64*64*64
#define N_IDX 131072  // 32*64*64
#define K_EMB 1024
#define D_EMB 64
#define EPS_GAP 1.25e-4f  // rigorous flip bound ~7e-5; 1.8x safety

typedef __attribute__((ext_vector_type(8))) short bf16x8;
typedef __attribute__((ext_vector_type(4))) float f32x4;

// f32 -> bf16 bits, round-to-nearest-even
__device__ __forceinline__ unsigned short f2bf(float f) {
  unsigned u = __builtin_bit_cast(unsigned, f);
  unsigned r = 0x7fffu + ((u >> 16) & 1u);
  return (unsigned short)((u + r) >> 16);
}
__device__ __forceinline__ float bf2f(unsigned short b) {
  return __builtin_bit_cast(float, (unsigned)b << 16);
}

__global__ __launch_bounds__(256) void ek2f_kernel(
    const float* __restrict__ emb, float* __restrict__ ek2f) {
  int k = blockIdx.x * 256 + threadIdx.x;   // 4 blocks -> 1024
  const float* row = emb + (size_t)k * D_EMB;
  float s = 0.0f;
  for (int d = 0; d < D_EMB; d++) {
    float e = row[d];
    float sq = e * e;
    asm volatile("" : "+v"(sq));   // block FMA-contraction / reassociation
    s = s + sq;
  }
  ek2f[k] = s;
}

// Pre-swizzle emb into MFMA B-fragment-linear bf16 hi/lo arrays.
// Fragment order: idx = ((kt*2 + sp)*64 + l)*8 + i  where
//   k = kt*16 + (l&15),  w = sp*32 + (l>>4)*8 + i,  value = e[k][w].
__global__ __launch_bounds__(256) void ebf_prep_kernel(
    const float* __restrict__ emb, unsigned short* __restrict__ ehi,
    unsigned short* __restrict__ elo) {
  int gid = blockIdx.x * 256 + threadIdx.x;   // 32 blocks -> 8192
  int k = gid >> 3, oct = gid & 7;            // w-octet = oct*8 .. oct*8+7
  const float* src = emb + (size_t)k * 64 + oct * 8;
  int kt = k >> 4, sp = oct >> 2, l = (oct & 3) * 16 + (k & 15);
  size_t off = ((size_t)((kt * 2 + sp) * 64 + l)) * 8;
  bf16x8 h8, l8;
  #pragma unroll
  for (int i = 0; i < 8; i++) {
    float v = src[i];
    unsigned short hb = f2bf(v);
    float lf = v - bf2f(hb);       // exact
    h8[i] = (short)hb;
    l8[i] = (short)f2bf(lf);
  }
  *(bf16x8*)(ehi + off) = h8;
  *(bf16x8*)(elo + off) = l8;
}

#define MFMA_BF16 __builtin_amdgcn_mfma_f32_16x16x32_bf16

// One block per TWO (b,h) tiles. 4 waves; wave wv owns c-rows [wv*16,wv*16+16)
// of both tiles. Main loop: 16 chunks x 4 kt; per kt read 4 fragment-sets from
// global and fire 12 MFMA (2 independent 6-chains). No barriers in the loop.
__global__ __launch_bounds__(256) void vq_main_kernel(
    const float* __restrict__ z, const float* __restrict__ emb,
    const float* __restrict__ ek2g,
    const unsigned short* __restrict__ ehi_g,
    const unsigned short* __restrict__ elo_g,
    float* __restrict__ out0, float* __restrict__ out_idx,
    double* __restrict__ loss_acc) {
  __shared__ __align__(16) float zts[2][64][64];   // [ti][w][c] 32 KB
  __shared__ float sk2[K_EMB];                     // 4 KB
  __shared__ float sa[2][64];
  __shared__ int sidx[2][64];
  __shared__ int sflag[2][64];
  __shared__ double lred[16];
  __shared__ float wrv[4];
  __shared__ int wri[4];

  const int t = threadIdx.x;
  const int bid2 = blockIdx.x;    // covers tiles bid2*2, bid2*2+1
  const int l = t & 63;           // lane
  const int cb = (t >> 6) * 16;   // wave c-base

  // ---- stage both z tiles [ti][w][c] AND write out[0] (= z) ----
  const float4* zt4 = (const float4*)(z + (size_t)bid2 * 8192);
  float4* o4 = (float4*)(out0 + (size_t)bid2 * 8192);
  #pragma unroll
  for (int q = 0; q < 8; q++) {
    int p = t + q * 256;          // 0..2047
    float4 v = zt4[p];
    int ti = p >> 10, p4 = p & 1023;
    *(float4*)&zts[ti][p4 >> 4][(p4 & 15) * 4] = v;
    o4[p] = v;
  }
  #pragma unroll
  for (int q = 0; q < 4; q++) sk2[t + q * 256] = ek2g[t + q * 256];
  __syncthreads();

  // ---- A[c]: strict sequential f32 sum of fl(z^2) (bit-exact, as R6/R7) ----
  if (t < 128) {
    int ti = t >> 6, cc = t & 63;
    float a = 0.0f;
    for (int w = 0; w < 64; w++) {
      float zf = zts[ti][w][cc];
      float sq = zf * zf;
      asm volatile("" : "+v"(sq));
      a = a + sq;
    }
    sa[ti][cc] = a;
  }

  // ---- persistent A-fragments (bf16 hi/lo) for both tiles ----
  // lane supplies row m = l&15 (c = cb+m), wloc = (l>>4)*8 + i, split sp.
  bf16x8 zh0_0, zh1_0, zl0_0, zl1_0, zh0_1, zh1_1, zl0_1, zl1_1;
  {
    const int crow = cb + (l & 15);
    const int wb = (l >> 4) * 8;
    #pragma unroll
    for (int i = 0; i < 8; i++) {
      float a0 = zts[0][wb + i][crow];
      unsigned short h0 = f2bf(a0);
      zh0_0[i] = (short)h0; zl0_0[i] = (short)f2bf(a0 - bf2f(h0));
      float a1 = zts[0][32 + wb + i][crow];
      unsigned short h1 = f2bf(a1);
      zh1_0[i] = (short)h1; zl1_0[i] = (short)f2bf(a1 - bf2f(h1));
      float b0 = zts[1][wb + i][crow];
      unsigned short g0 = f2bf(b0);
      zh0_1[i] = (short)g0; zl0_1[i] = (short)f2bf(b0 - bf2f(g0));
      float b1 = zts[1][32 + wb + i][crow];
      unsigned short g1 = f2bf(b1);
      zh1_1[i] = (short)g1; zl1_1[i] = (short)f2bf(b1 - bf2f(g1));
    }
  }
  __syncthreads();   // sa visible

  float A0_[4], A1_[4];
  #pragma unroll
  for (int i = 0; i < 4; i++) {
    A0_[i] = sa[0][cb + (l >> 4) * 4 + i];
    A1_[i] = sa[1][cb + (l >> 4) * 4 + i];
  }

  float m1[2][4], m2[2][4];
  int i1[2][4];
  #pragma unroll
  for (int ti = 0; ti < 2; ti++)
    #pragma unroll
    for (int i = 0; i < 4; i++) { m1[ti][i] = 3.0e38f; m2[ti][i] = 3.0e38f; i1[ti][i] = 0; }

  // ---- main loop: 64 kt of 16 k each; barrier-free ----
  for (int ch = 0; ch < 16; ch++) {
    #pragma unroll
    for (int t4 = 0; t4 < 4; t4++) {
      const int kt = ch * 4 + t4;
      const size_t fo = (size_t)kt * 1024 + (size_t)l * 8;  // shorts
      bf16x8 bh0 = *(const bf16x8*)(ehi_g + fo);
      bf16x8 bh1 = *(const bf16x8*)(ehi_g + fo + 512);
      bf16x8 bl0 = *(const bf16x8*)(elo_g + fo);
      bf16x8 bl1 = *(const bf16x8*)(elo_g + fo + 512);

      f32x4 a0 = {0.f, 0.f, 0.f, 0.f}, a1 = {0.f, 0.f, 0.f, 0.f};
      a0 = MFMA_BF16(zh0_0, bh0, a0, 0, 0, 0);
      a1 = MFMA_BF16(zh0_1, bh0, a1, 0, 0, 0);
      a0 = MFMA_BF16(zh1_0, bh1, a0, 0, 0, 0);
      a1 = MFMA_BF16(zh1_1, bh1, a1, 0, 0, 0);
      a0 = MFMA_BF16(zh0_0, bl0, a0, 0, 0, 0);
      a1 = MFMA_BF16(zh0_1, bl0, a1, 0, 0, 0);
      a0 = MFMA_BF16(zh1_0, bl1, a0, 0, 0, 0);
      a1 = MFMA_BF16(zh1_1, bl1, a1, 0, 0, 0);
      a0 = MFMA_BF16(zl0_0, bh0, a0, 0, 0, 0);
      a1 = MFMA_BF16(zl0_1, bh0, a1, 0, 0, 0);
      a0 = MFMA_BF16(zl1_0, bh1, a0, 0, 0, 0);
      a1 = MFMA_BF16(zl1_1, bh1, a1, 0, 0, 0);

      // C/D: col k = l&15, row c = cb + (l>>4)*4 + i
      const int k = kt * 16 + (l & 15);
      const float ck = sk2[k];
      #pragma unroll
      for (int i = 0; i < 4; i++) {
        float sc0 = fmaf(-2.0f, a0[i], A0_[i]) + ck;
        if (sc0 < m1[0][i]) { m2[0][i] = m1[0][i]; m1[0][i] = sc0; i1[0][i] = k; }
        else                { m2[0][i] = fminf(m2[0][i], sc0); }
        float sc1 = fmaf(-2.0f, a1[i], A1_[i]) + ck;
        if (sc1 < m1[1][i]) { m2[1][i] = m1[1][i]; m1[1][i] = sc1; i1[1][i] = k; }
        else                { m2[1][i] = fminf(m2[1][i], sc1); }
      }
    }
  }

  // ---- 16-lane top-2 lex merge per (ti, c) ----
  #pragma unroll
  for (int ti = 0; ti < 2; ti++) {
    #pragma unroll
    for (int ci = 0; ci < 4; ci++) {
      float v1 = m1[ti][ci], v2 = m2[ti][ci];
      int ix = i1[ti][ci];
      #pragma unroll
      for (int m = 8; m; m >>= 1) {
        float ov1 = __shfl_xor(v1, m, 16);
        int oi1 = __shfl_xor(ix, m, 16);
        float ov2 = __shfl_xor(v2, m, 16);
        if (ov1 < v1)      { v2 = fminf(v1, ov2); v1 = ov1; ix = oi1; }
        else if (ov1 > v1) { v2 = fminf(v2, ov1); }
        else               { v2 = v1; ix = min(ix, oi1); }   // tie -> force flag
      }
      if ((l & 15) == 0) {
        int c = cb + (l >> 4) * 4 + ci;
        sidx[ti][c] = ix;
        sflag[ti][c] = (v2 - v1 <= EPS_GAP) ? 1 : 0;
      }
    }
  }
  __syncthreads();

  // ---- Phase B: exact re-scan of flagged rows (rare) — R7 semantics ----
  #pragma unroll 1
  for (int ti = 0; ti < 2; ti++) {
    #pragma unroll 1
    for (int c = 0; c < 64; c++) {
      if (!sflag[ti][c]) continue;             // uniform
      float A = sa[ti][c];
      float lm = 3.0e38f;
      int li = 0;
      #pragma unroll
      for (int r = 0; r < 4; r++) {
        int k = t + 256 * r;
        double B = 0.0;
        const float4* e4 = (const float4*)(emb + (size_t)k * 64);
        for (int w4 = 0; w4 < 16; w4++) {
          float4 e = e4[w4];
          B += (double)zts[ti][w4 * 4 + 0][c] * (double)e.x;
          B += (double)zts[ti][w4 * 4 + 1][c] * (double)e.y;
          B += (double)zts[ti][w4 * 4 + 2][c] * (double)e.z;
          B += (double)zts[ti][w4 * 4 + 3][c] * (double)e.w;
        }
        float Bf = (float)B;
        float t1 = A - 2.0f * Bf;              // 2*Bf exact -> single rounding
        float sc = t1 + sk2[k];
        if (sc < lm) { lm = sc; li = k; }      // k ascending -> first-min kept
      }
      #pragma unroll
      for (int m = 32; m; m >>= 1) {
        float ov = __shfl_xor(lm, m);
        int oi = __shfl_xor(li, m);
        if (ov < lm || (ov == lm && oi < li)) { lm = ov; li = oi; }
      }
      if ((t & 63) == 0) { wrv[t >> 6] = lm; wri[t >> 6] = li; }
      __syncthreads();
      if (t == 0) {
        float bv = wrv[0]; int bi = wri[0];
        #pragma unroll
        for (int q = 1; q < 4; q++) {
          if (wrv[q] < bv || (wrv[q] == bv && wri[q] < bi)) { bv = wrv[q]; bi = wri[q]; }
        }
        sidx[ti][c] = bi;
      }
      __syncthreads();
    }
  }
  __syncthreads();

  // ---- write indices ----
  if (t < 128) {
    int ti = t >> 6, cc = t & 63;
    int tile = bid2 * 2 + ti;
    int b = tile >> 6, h = tile & 63;
    out_idx[(size_t)b * 4096 + cc * 64 + h] = (float)sidx[ti][cc];
  }

  // ---- loss: sum (z - e[idx])^2 in f64 (R7 semantics, both tiles) ----
  double ls = 0.0;
  #pragma unroll
  for (int ti = 0; ti < 2; ti++) {
    #pragma unroll
    for (int ci = 0; ci < 4; ci++) {
      int c = (t >> 4) * 4 + ci;
      const float* er = emb + (size_t)sidx[ti][c] * 64;
      #pragma unroll
      for (int s = 0; s < 4; s++) {
        int w = (t & 15) + 16 * s;
        double d = (double)zts[ti][w][c] - (double)er[w];
        ls += d * d;
      }
    }
  }
  #pragma unroll
  for (int m = 8; m; m >>= 1) ls += __shfl_xor(ls, m, 16);
  if ((t & 15) == 0) lred[t >> 4] = ls;
  __syncthreads();
  if (t == 0) {
    double s = 0.0;
    #pragma unroll
    for (int q = 0; q < 16; q++) s += lred[q];
    atomicAdd(loss_acc, s);
  }
}

__global__ void loss_final_kernel(const double* __restrict__ acc,
                                  float* __restrict__ out_loss) {
  *out_loss = (float)(0.25 * (*acc) / (double)N_Z);
}

extern "C" void kernel_launch(void* const* d_in, const int* in_sizes, int n_in,
                              void* d_out, int out_size, void* d_ws, size_t ws_size,
                              hipStream_t stream) {
  const float* z = (const float*)d_in[0];     // [32,64,64,64] NHWC
  const float* emb = (const float*)d_in[1];   // [1024,64]
  float* out = (float*)d_out;

  float* ek2f = (float*)d_ws;                              // 4 KB @ 0
  double* lacc = (double*)((char*)d_ws + 4096);            // 8 B
  unsigned short* ehi = (unsigned short*)((char*)d_ws + 8192);    // 128 KB
  unsigned short* elo = (unsigned short*)((char*)d_ws + 8192 + 131072); // 128 KB

  (void)hipMemsetAsync(lacc, 0, sizeof(double), stream);
  ek2f_kernel<<<4, 256, 0, stream>>>(emb, ek2f);
  ebf_prep_kernel<<<32, 256, 0, stream>>>(emb, ehi, elo);
  vq_main_kernel<<<1024, 256, 0, stream>>>(z, emb, ek2f, ehi, elo,
                                           out, out + N_Z, lacc);
  loss_final_kernel<<<1, 1, 0, stream>>>(lacc, out + N_Z + N_IDX);
}